// Round 11
// baseline (355.646 us; speedup 1.0000x reference)
//
#include <hip/hip_runtime.h>
#include <math.h>

#define BZ 2
#define SQ 2048
#define DIN 1024
#define HH 16
#define NT 6144
#define MROWS 4096
#define KOUT 2048
#define KSPLIT 16

typedef unsigned short u16t;
typedef unsigned int u32t;
typedef __attribute__((ext_vector_type(8))) short bf16x8;
typedef __attribute__((ext_vector_type(4))) float f32x4;

__device__ __forceinline__ float cubef(float x) { return x * x * x; }

__device__ __forceinline__ u16t f2bf(float f) {          // fp32 -> bf16 RNE (unbiased)
    u32t b = __float_as_uint(f);
    b += 0x7FFFu + ((b >> 16) & 1u);
    return (u16t)(b >> 16);
}
__device__ __forceinline__ float bf2f(u16t u) { return __uint_as_float(((u32t)u) << 16); }
__device__ __forceinline__ u32t pk2(float a, float b) {
    return (u32t)f2bf(a) | ((u32t)f2bf(b) << 16);
}

// ---------------- K0x: x fp32 -> xb bf16 RNE ----------------
__global__ __launch_bounds__(256) void bf16_x(const float* __restrict__ x,
                                              u16t* __restrict__ xb) {
    const size_t idx = ((size_t)blockIdx.x * 256 + threadIdx.x) * 8;
    float4 f0 = *(const float4*)&x[idx];
    float4 f1 = *(const float4*)&x[idx + 4];
    u32t h[4];
    h[0] = pk2(f0.x, f0.y); h[1] = pk2(f0.z, f0.w);
    h[2] = pk2(f1.x, f1.y); h[3] = pk2(f1.z, f1.w);
    *(uint4*)&xb[idx] = *(uint4*)&h[0];
}

// ---------------- K0a: proj_in [k][n] fp32 -> pTh [n][k] bf16 RNE ----------------
__global__ __launch_bounds__(256) void transpose_w(const float* __restrict__ W,
                                                   u16t* __restrict__ Th) {
    __shared__ float tile[64][68];
    const int n0 = blockIdx.x * 64;
    const int k0 = blockIdx.y * 64;
    const int t = threadIdx.x;
    {
        const int r = t >> 4, c = (t & 15) * 4;
        #pragma unroll
        for (int p = 0; p < 4; p++) {
            float4 v = *(const float4*)&W[(size_t)(k0 + r + p * 16) * NT + n0 + c];
            *(float4*)&tile[r + p * 16][c] = v;
        }
    }
    __syncthreads();
    const int nr = t >> 2;
    const int kc = (t & 3) * 16;
    u32t hi[8];
    #pragma unroll
    for (int j = 0; j < 8; j++)
        hi[j] = pk2(tile[kc + 2 * j][nr], tile[kc + 2 * j + 1][nr]);
    size_t ob = (size_t)(n0 + nr) * DIN + k0 + kc;
    *(uint4*)&Th[ob]     = *(uint4*)&hi[0];
    *(uint4*)&Th[ob + 8] = *(uint4*)&hi[4];
}

// ---------------- K0b: proj_out [k][y] fp32 -> WTh [y][k] bf16 RNE ----------------
__global__ __launch_bounds__(256) void transpose_w2(const float* __restrict__ W,
                                                    u16t* __restrict__ Th) {
    __shared__ float tile[64][68];
    const int n0 = blockIdx.x * 64;
    const int k0 = blockIdx.y * 64;
    const int t = threadIdx.x;
    {
        const int r = t >> 4, c = (t & 15) * 4;
        #pragma unroll
        for (int p = 0; p < 4; p++) {
            float4 v = *(const float4*)&W[(size_t)(k0 + r + p * 16) * 128 + n0 + c];
            *(float4*)&tile[r + p * 16][c] = v;
        }
    }
    __syncthreads();
    const int nr = t >> 2;
    const int kc = (t & 3) * 16;
    u32t hi[8];
    #pragma unroll
    for (int j = 0; j < 8; j++)
        hi[j] = pk2(tile[kc + 2 * j][nr], tile[kc + 2 * j + 1][nr]);
    size_t ob = (size_t)(n0 + nr) * KOUT + k0 + kc;
    *(uint4*)&Th[ob]     = *(uint4*)&hi[0];
    *(uint4*)&Th[ob + 8] = *(uint4*)&hi[4];
}

// ---------------- K1: qkv GEMM — pipelined dbuf, 1 barrier/iter, head-major epilogue ----------------
__global__ __launch_bounds__(256) void gemm_qkv4(const u16t* __restrict__ Ah,
                                                 const u16t* __restrict__ Bh,
                                                 const float* __restrict__ vb,
                                                 u16t* __restrict__ QB,
                                                 u16t* __restrict__ KB,
                                                 u16t* __restrict__ VF) {
    __shared__ __align__(16) u16t as_h[2][4 * 128 * 8];
    __shared__ __align__(16) u16t bs_h[2][4 * 128 * 8];

    const int t = threadIdx.x;
    const int lane = t & 63, wid = t >> 6;
    const int quad = lane >> 4, l15 = lane & 15;
    const int wm = (wid & 1) * 64;
    const int wn = (wid >> 1) * 64;
    const int tile = blockIdx.x;               // 0..47 = h*3 + {q,k,v}
    const int h = tile / 3, t3 = tile - h * 3;
    const int colBase = tile * 128;
    const int rowBase = blockIdx.y * 128;
    const int sm = t & 127;
    const int skh = t >> 7;

    f32x4 acc[4][4];
    #pragma unroll
    for (int i = 0; i < 4; i++)
        #pragma unroll
        for (int j = 0; j < 4; j++) acc[i][j] = (f32x4){0.f, 0.f, 0.f, 0.f};

    const u16t* aPtr = Ah + (size_t)(rowBase + sm) * DIN + skh * 16;
    const u16t* bPtr = Bh + (size_t)(colBase + sm) * DIN + skh * 16;
    const int swoff = (skh * 2) * 1024 + sm * 8;

    // prefetch tile 0
    uint4 a0 = *(const uint4*)(aPtr);
    uint4 a1 = *(const uint4*)(aPtr + 8);
    uint4 b0 = *(const uint4*)(bPtr);
    uint4 b1 = *(const uint4*)(bPtr + 8);

    for (int it = 0; it < 32; it++) {
        const int buf = it & 1;
        // commit (vmcnt waits here; loads had full prior compute phase)
        *(uint4*)(&as_h[buf][swoff])        = a0;
        *(uint4*)(&as_h[buf][swoff + 1024]) = a1;
        *(uint4*)(&bs_h[buf][swoff])        = b0;
        *(uint4*)(&bs_h[buf][swoff + 1024]) = b1;
        __syncthreads();          // no VM in flight -> cheap drain
        // issue next tile's loads (overlap compute below)
        {
            const int k0 = (it < 31) ? (it + 1) * 32 : it * 32;
            a0 = *(const uint4*)(aPtr + k0);
            a1 = *(const uint4*)(aPtr + k0 + 8);
            b0 = *(const uint4*)(bPtr + k0);
            b1 = *(const uint4*)(bPtr + k0 + 8);
        }
        bf16x8 ah[4], bh[4];
        #pragma unroll
        for (int mt = 0; mt < 4; mt++)
            ah[mt] = *(const bf16x8*)&as_h[buf][quad * 1024 + (wm + mt * 16 + l15) * 8];
        #pragma unroll
        for (int nt = 0; nt < 4; nt++)
            bh[nt] = *(const bf16x8*)&bs_h[buf][quad * 1024 + (wn + nt * 16 + l15) * 8];
        #pragma unroll
        for (int mt = 0; mt < 4; mt++)
            #pragma unroll
            for (int nt = 0; nt < 4; nt++)
                acc[mt][nt] = __builtin_amdgcn_mfma_f32_16x16x32_bf16(ah[mt], bh[nt], acc[mt][nt], 0, 0, 0);
    }

    const int z = rowBase >> 11;
    const int s0 = (rowBase & 2047) + wm + quad * 4;
    const size_t obase = (size_t)(z * 16 + h) * 2048;
    if (t3 == 2) {
        #pragma unroll
        for (int nt = 0; nt < 4; nt++) {
            int c = wn + nt * 16 + l15;
            float bb = vb[h * 128 + c];
            #pragma unroll
            for (int mt = 0; mt < 4; mt++)
                #pragma unroll
                for (int r = 0; r < 4; r++)
                    VF[(obase + s0 + mt * 16 + r) * 128 + c] = f2bf(acc[mt][nt][r] + bb);
        }
    } else {
        u16t* dst = t3 ? KB : QB;
        #pragma unroll
        for (int nt = 0; nt < 4; nt++) {
            int c = wn + nt * 16 + l15;
            #pragma unroll
            for (int mt = 0; mt < 4; mt++)
                #pragma unroll
                for (int r = 0; r < 4; r++)
                    dst[(obase + s0 + mt * 16 + r) * 128 + c] = f2bf(acc[mt][nt][r]);
        }
    }
}

// ---------------- K2: rotary in-place on QB/KB; V tile-transpose in-place ----------------
__global__ __launch_bounds__(256) void prep_rot_trans(u16t* __restrict__ QB,
                                                      u16t* __restrict__ KB,
                                                      u16t* __restrict__ VTh) {
    const int bx = blockIdx.x;
    const int st = bx & 63, h = (bx >> 6) & 15, z = bx >> 10;
    const int t = threadIdx.x;
    const size_t base = ((size_t)(z * 16 + h) * 2048 + st * 32) * 128;

    {
        const int r = t >> 3, w = t & 7;
        const int c = w & 3;
        const int s = st * 32 + r;
        u16t* buf = (w < 4) ? QB : KB;
        u16t* p1 = buf + base + (size_t)r * 128 + c * 16;
        u16t* p2 = p1 + 64;
        uint4 a0 = *(uint4*)p1, a1 = *(uint4*)(p1 + 8);
        uint4 b0 = *(uint4*)p2, b1 = *(uint4*)(p2 + 8);
        u32t A[8] = {a0.x, a0.y, a0.z, a0.w, a1.x, a1.y, a1.z, a1.w};
        u32t B[8] = {b0.x, b0.y, b0.z, b0.w, b1.x, b1.y, b1.z, b1.w};
        u32t OA[8], OB[8];
        #pragma unroll
        for (int p = 0; p < 8; p++) {
            float x1a = bf2f((u16t)(A[p] & 0xFFFFu)), x1b = bf2f((u16t)(A[p] >> 16));
            float x2a = bf2f((u16t)(B[p] & 0xFFFFu)), x2b = bf2f((u16t)(B[p] >> 16));
            int j0 = c * 16 + 2 * p;
            float f0 = expf(-0.14391156831212788f * (float)j0);
            float f1 = expf(-0.14391156831212788f * (float)(j0 + 1));
            float sn0, cs0, sn1, cs1;
            sincosf((float)s * f0, &sn0, &cs0);
            sincosf((float)s * f1, &sn1, &cs1);
            OA[p] = pk2(x1a * cs0 - x2a * sn0, x1b * cs1 - x2b * sn1);
            OB[p] = pk2(x2a * cs0 + x1a * sn0, x2b * cs1 + x1b * sn1);
        }
        *(uint4*)p1       = make_uint4(OA[0], OA[1], OA[2], OA[3]);
        *(uint4*)(p1 + 8) = make_uint4(OA[4], OA[5], OA[6], OA[7]);
        *(uint4*)p2       = make_uint4(OB[0], OB[1], OB[2], OB[3]);
        *(uint4*)(p2 + 8) = make_uint4(OB[4], OB[5], OB[6], OB[7]);
    }

    __shared__ u16t vt[128 * 40];
    {
        uint4 a = *(uint4*)(VTh + base + t * 16);
        uint4 b = *(uint4*)(VTh + base + t * 16 + 8);
        int row = t >> 3, d0 = (t & 7) * 16;
        u32t W[8] = {a.x, a.y, a.z, a.w, b.x, b.y, b.z, b.w};
        #pragma unroll
        for (int p = 0; p < 8; p++) {
            vt[(d0 + 2 * p) * 40 + row]     = (u16t)(W[p] & 0xFFFFu);
            vt[(d0 + 2 * p + 1) * 40 + row] = (u16t)(W[p] >> 16);
        }
    }
    __syncthreads();
    {
        int d = t >> 1, k0 = (t & 1) * 16;
        uint4 a = *(uint4*)&vt[d * 40 + k0];
        uint4 b = *(uint4*)&vt[d * 40 + k0 + 8];
        *(uint4*)(VTh + base + t * 16)     = a;
        *(uint4*)(VTh + base + t * 16 + 8) = b;
    }
}

// ---------------- K3: attention v6 — 64q blocks, dbuf, loads-after-barrier, 1 barrier/iter ----------------
#define ATTSCALE 0.08838834764831845f

__global__ __launch_bounds__(256, 3) void attn_kernel6(const u16t* __restrict__ QB,
                                                       const u16t* __restrict__ KB,
                                                       const u16t* __restrict__ VTh,
                                                       const int* __restrict__ mask,
                                                       u16t* __restrict__ O3b) {
    const int blk = blockIdx.x;
    const int qt = blk & 31;           // 32 q-blocks of 64
    const int h  = (blk >> 5) & 15;
    const int z  = blk >> 9;
    const int t  = threadIdx.x;
    const int lane = t & 63, wid = t >> 6;
    const int quad = lane >> 4, l15 = lane & 15;

    __shared__ __align__(16) u16t ks[2][32 * 136];   // K bf16 [key][d]
    __shared__ __align__(16) u16t vth[2][128 * 40];  // V^T bf16 [d][key]
    __shared__ __align__(16) u16t wlb[64 * 40];      // P bf16 [q][key] (wave-private rows)
    __shared__ int qm[64], km[2][32];

    const int q0 = qt * 64;
    const size_t zh = (size_t)(z * 16 + h);
    const u16t* qb  = QB  + zh * 262144;
    const u16t* kb  = KB  + zh * 262144;
    const u16t* vhg = VTh + zh * 262144;

    // wave owns q-16-tile 'wid'
    bf16x8 qf[4];
    #pragma unroll
    for (int kk = 0; kk < 4; kk++)
        qf[kk] = *(const bf16x8*)(qb + (size_t)(q0 + 16 * wid + l15) * 128 + kk * 32 + quad * 8);
    if (t < 64) qm[t] = mask[z * SQ + q0 + t];

    const int srow = t >> 3, sco = (t & 7) * 16;     // K staging map
    const int sdd = t >> 1, sk0 = (t & 1) * 16;      // V staging map

    // prefetch tile 0
    uint4 ka, kb2, va, vb2;
    int kmv = 0;
    {
        ka  = *(const uint4*)(kb + t * 16);
        kb2 = *(const uint4*)(kb + t * 16 + 8);
        va  = *(const uint4*)(vhg + t * 16);
        vb2 = *(const uint4*)(vhg + t * 16 + 8);
        if (t < 32) kmv = mask[z * SQ + t];
    }

    f32x4 acc[8];
    #pragma unroll
    for (int d = 0; d < 8; d++) acc[d] = (f32x4){0.f, 0.f, 0.f, 0.f};
    float dsum[4] = {0.f, 0.f, 0.f, 0.f};

    for (int it = 0; it < 64; it++) {
        const int buf = it & 1;
        // commit prefetched tile (vmcnt waits here, after a full compute phase in flight)
        *(uint4*)&ks[buf][srow * 136 + sco]     = ka;
        *(uint4*)&ks[buf][srow * 136 + sco + 8] = kb2;
        *(uint4*)&vth[buf][sdd * 40 + sk0]      = va;
        *(uint4*)&vth[buf][sdd * 40 + sk0 + 8]  = vb2;
        if (t < 32) km[buf][t] = kmv;

        __syncthreads();   // no VM outstanding -> cheap; publishes buf

        // issue next tile's loads AFTER the barrier (overlap the compute below)
        {
            const int ktn = (it < 63) ? (it + 1) * 32 : it * 32;
            const u16t* src = kb + (size_t)ktn * 128 + t * 16;
            ka  = *(const uint4*)(src);
            kb2 = *(const uint4*)(src + 8);
            const u16t* srch = vhg + (size_t)(ktn >> 5) * 4096 + t * 16;
            va  = *(const uint4*)(srch);
            vb2 = *(const uint4*)(srch + 8);
            if (t < 32) kmv = mask[z * SQ + ktn + t];
        }

        // QK^T: 1 q-tile x 2 key-cols
        f32x4 s4[2] = {(f32x4){0.f, 0.f, 0.f, 0.f}, (f32x4){0.f, 0.f, 0.f, 0.f}};
        #pragma unroll
        for (int kk = 0; kk < 4; kk++) {
            bf16x8 kf0 = *(const bf16x8*)&ks[buf][l15 * 136 + kk * 32 + quad * 8];
            bf16x8 kf1 = *(const bf16x8*)&ks[buf][(16 + l15) * 136 + kk * 32 + quad * 8];
            s4[0] = __builtin_amdgcn_mfma_f32_16x16x32_bf16(qf[kk], kf0, s4[0], 0, 0, 0);
            s4[1] = __builtin_amdgcn_mfma_f32_16x16x32_bf16(qf[kk], kf1, s4[1], 0, 0, 0);
        }
        {   // mask + exp -> bf16 P into wave-private LDS rows; fp32 denominator
            int colm0 = km[buf][l15], colm1 = km[buf][16 + l15];
            #pragma unroll
            for (int r = 0; r < 4; r++) {
                int row = 16 * wid + 4 * quad + r;
                int qmr = qm[row];
                float w0 = (qmr | colm0) ? 0.f : __expf(s4[0][r] * ATTSCALE);
                float w1 = (qmr | colm1) ? 0.f : __expf(s4[1][r] * ATTSCALE);
                dsum[r] += w0 + w1;
                wlb[row * 40 + l15]      = f2bf(w0);
                wlb[row * 40 + 16 + l15] = f2bf(w1);
            }
        }
        // P·V: same-wave read-back (wave-private rows; lgkm ordering, no barrier)
        bf16x8 pa = *(const bf16x8*)&wlb[(16 * wid + l15) * 40 + quad * 8];
        #pragma unroll
        for (int dt = 0; dt < 8; dt++) {
            bf16x8 vh = *(const bf16x8*)&vth[buf][(16 * dt + l15) * 40 + quad * 8];
            acc[dt] = __builtin_amdgcn_mfma_f32_16x16x32_bf16(pa, vh, acc[dt], 0, 0, 0);
        }
    }

    // denominator: complete within wave — 16-lane shuffle reduce
    #pragma unroll
    for (int r = 0; r < 4; r++) {
        float v = dsum[r];
        v += __shfl_xor(v, 1);
        v += __shfl_xor(v, 2);
        v += __shfl_xor(v, 4);
        v += __shfl_xor(v, 8);
        dsum[r] = v;
    }

    // epilogue: normalize, cube, write bf16 O in [m=z*2048+s][k=h*128+d]
    #pragma unroll
    for (int r = 0; r < 4; r++) {
        int row = 16 * wid + 4 * quad + r;
        float inv = dsum[r] > 0.f ? 1.f / dsum[r] : 0.f;
        u16t* dst = O3b + (size_t)(z * SQ + q0 + row) * KOUT + h * 128;
        #pragma unroll
        for (int dt = 0; dt < 8; dt++)
            dst[16 * dt + l15] = f2bf(cubef(acc[dt][r] * inv));
    }
}

// ---------------- K4: partial[s] = O3b[:, chunk] @ W[chunk, :] — pipelined, KSPLIT=16 ----------------
__global__ __launch_bounds__(256) void final_gemm3(const u16t* __restrict__ Ab,
                                                   const u16t* __restrict__ Bh,
                                                   float* __restrict__ part) {
    __shared__ __align__(16) u16t as_h[2][4 * 128 * 8];
    __shared__ __align__(16) u16t bs_h[2][4 * 128 * 8];

    const int t = threadIdx.x;
    const int lane = t & 63, wid = t >> 6;
    const int quad = lane >> 4, l15 = lane & 15;
    const int wm = (wid & 1) * 64;
    const int wn = (wid >> 1) * 64;
    const int rowBase = blockIdx.x * 128;
    const int kBase   = blockIdx.y * (KOUT / KSPLIT);   // 128
    const int sm = t & 127;
    const int skh = t >> 7;

    f32x4 acc[4][4];
    #pragma unroll
    for (int i = 0; i < 4; i++)
        #pragma unroll
        for (int j = 0; j < 4; j++) acc[i][j] = (f32x4){0.f, 0.f, 0.f, 0.f};

    const u16t* aPtr = Ab + (size_t)(rowBase + sm) * KOUT + kBase + skh * 16;
    const u16t* bPtr = Bh + (size_t)sm * KOUT + kBase + skh * 16;
    const int swoff = (skh * 2) * 1024 + sm * 8;

    uint4 a0 = *(const uint4*)(aPtr);
    uint4 a1 = *(const uint4*)(aPtr + 8);
    uint4 b0 = *(const uint4*)(bPtr);
    uint4 b1 = *(const uint4*)(bPtr + 8);

    const int NIT = (KOUT / KSPLIT) / 32;   // 4
    for (int it = 0; it < NIT; it++) {
        const int buf = it & 1;
        *(uint4*)(&as_h[buf][swoff])        = a0;
        *(uint4*)(&as_h[buf][swoff + 1024]) = a1;
        *(uint4*)(&bs_h[buf][swoff])        = b0;
        *(uint4*)(&bs_h[buf][swoff + 1024]) = b1;
        __syncthreads();
        {
            const int k0 = (it < NIT - 1) ? (it + 1) * 32 : it * 32;
            a0 = *(const uint4*)(aPtr + k0);
            a1 = *(const uint4*)(aPtr + k0 + 8);
            b0 = *(const uint4*)(bPtr + k0);
            b1 = *(const uint4*)(bPtr + k0 + 8);
        }
        bf16x8 ah[4], bh[4];
        #pragma unroll
        for (int mt = 0; mt < 4; mt++)
            ah[mt] = *(const bf16x8*)&as_h[buf][quad * 1024 + (wm + mt * 16 + l15) * 8];
        #pragma unroll
        for (int nt = 0; nt < 4; nt++)
            bh[nt] = *(const bf16x8*)&bs_h[buf][quad * 1024 + (wn + nt * 16 + l15) * 8];
        #pragma unroll
        for (int mt = 0; mt < 4; mt++)
            #pragma unroll
            for (int nt = 0; nt < 4; nt++)
                acc[mt][nt] = __builtin_amdgcn_mfma_f32_16x16x32_bf16(ah[mt], bh[nt], acc[mt][nt], 0, 0, 0);
    }

    float* pbase = part + (size_t)blockIdx.y * ((size_t)MROWS * 128);
    #pragma unroll
    for (int mt = 0; mt < 4; mt++)
        #pragma unroll
        for (int nt = 0; nt < 4; nt++) {
            int col = wn + nt * 16 + l15;
            #pragma unroll
            for (int r = 0; r < 4; r++) {
                int row = rowBase + wm + mt * 16 + quad * 4 + r;
                pbase[(size_t)row * 128 + col] = acc[mt][nt][r];
            }
        }
}

// ---------------- K5: out = cube(sum partials + bias) ----------------
__global__ __launch_bounds__(256) void reduce_bias_cube(const float* __restrict__ part,
                                                        const float* __restrict__ bias,
                                                        float* __restrict__ out) {
    const int idx = (blockIdx.x * 256 + threadIdx.x) * 4;
    float4 s = {0.f, 0.f, 0.f, 0.f};
    #pragma unroll
    for (int p = 0; p < KSPLIT; p++) {
        float4 v = *(const float4*)&part[(size_t)p * ((size_t)MROWS * 128) + idx];
        s.x += v.x; s.y += v.y; s.z += v.z; s.w += v.w;
    }
    float4 b = *(const float4*)&bias[idx & 127];
    float4 r;
    r.x = cubef(s.x + b.x);
    r.y = cubef(s.y + b.y);
    r.z = cubef(s.z + b.z);
    r.w = cubef(s.w + b.w);
    *(float4*)&out[idx] = r;
}

extern "C" void kernel_launch(void* const* d_in, const int* in_sizes, int n_in,
                              void* d_out, int out_size, void* d_ws, size_t ws_size,
                              hipStream_t stream) {
    const float* x        = (const float*)d_in[0];
    const int*   mask     = (const int*)d_in[1];
    const float* proj_in  = (const float*)d_in[2];
    const float* v_bias   = (const float*)d_in[3];
    const float* proj_out = (const float*)d_in[4];
    const float* po_bias  = (const float*)d_in[5];
    float* out = (float*)d_out;

    // ws layout (~72 MB):
    u16t* QB  = (u16t*)d_ws;                      // [z,h,s,d] bf16 16 MB
    u16t* KB  = QB + (size_t)8388608;             // 16 MB
    u16t* VTh = KB + (size_t)8388608;             // 16 MB ([s][d] from gemm, [d][s]-tiled after prep)
    u16t* xb  = VTh + (size_t)8388608;            // [4096,1024] bf16 8 MB
    u16t* O3b = xb + (size_t)4194304;             // [4096,2048] bf16 16 MB
    // pTh aliases O3b (dead before attn writes O3b; gemm reads complete first — stream order)
    u16t* pTh = O3b;                              // [6144,1024] bf16 12.6 MB
    // WTh + partials alias QB..VTh region (48 MB, dead after attn)
    u16t* WTh = QB;                               // [128,2048] bf16 0.5 MB
    float* partials = (float*)(WTh + (size_t)128 * KOUT);  // [16,4096,128] f32 33.5 MB

    bf16_x<<<(MROWS * DIN) / (256 * 8), 256, 0, stream>>>(x, xb);
    transpose_w<<<dim3(NT / 64, DIN / 64), 256, 0, stream>>>(proj_in, pTh);
    gemm_qkv4<<<dim3(48, MROWS / 128), 256, 0, stream>>>(xb, pTh, v_bias, QB, KB, VTh);
    prep_rot_trans<<<BZ * HH * (SQ / 32), 256, 0, stream>>>(QB, KB, VTh);
    attn_kernel6<<<BZ * HH * (SQ / 64), 256, 0, stream>>>(QB, KB, VTh, mask, O3b);
    transpose_w2<<<dim3(2, KOUT / 64), 256, 0, stream>>>(proj_out, WTh);
    final_gemm3<<<dim3(MROWS / 128, KSPLIT), 256, 0, stream>>>(O3b, WTh, partials);
    reduce_bias_cube<<<(MROWS * 128) / (256 * 4), 256, 0, stream>>>(partials, po_bias, out);
}

// Round 12
// 328.776 us; speedup vs baseline: 1.0817x; 1.0817x over previous
//
#include <hip/hip_runtime.h>
#include <math.h>

#define BZ 2
#define SQ 2048
#define DIN 1024
#define HH 16
#define NT 6144
#define MROWS 4096
#define KOUT 2048
#define KSPLIT 16

typedef unsigned short u16t;
typedef unsigned int u32t;
typedef __attribute__((ext_vector_type(8))) short bf16x8;
typedef __attribute__((ext_vector_type(4))) float f32x4;

__device__ __forceinline__ float cubef(float x) { return x * x * x; }

__device__ __forceinline__ u16t f2bf(float f) {          // fp32 -> bf16 RNE (unbiased)
    u32t b = __float_as_uint(f);
    b += 0x7FFFu + ((b >> 16) & 1u);
    return (u16t)(b >> 16);
}
__device__ __forceinline__ float bf2f(u16t u) { return __uint_as_float(((u32t)u) << 16); }
__device__ __forceinline__ u32t pk2(float a, float b) {
    return (u32t)f2bf(a) | ((u32t)f2bf(b) << 16);
}

// ---------------- K0x: x fp32 -> xb bf16 RNE ----------------
__global__ __launch_bounds__(256) void bf16_x(const float* __restrict__ x,
                                              u16t* __restrict__ xb) {
    const size_t idx = ((size_t)blockIdx.x * 256 + threadIdx.x) * 8;
    float4 f0 = *(const float4*)&x[idx];
    float4 f1 = *(const float4*)&x[idx + 4];
    u32t h[4];
    h[0] = pk2(f0.x, f0.y); h[1] = pk2(f0.z, f0.w);
    h[2] = pk2(f1.x, f1.y); h[3] = pk2(f1.z, f1.w);
    *(uint4*)&xb[idx] = *(uint4*)&h[0];
}

// ---------------- K0a: proj_in [k][n] fp32 -> pTh [n][k] bf16 RNE ----------------
__global__ __launch_bounds__(256) void transpose_w(const float* __restrict__ W,
                                                   u16t* __restrict__ Th) {
    __shared__ float tile[64][68];
    const int n0 = blockIdx.x * 64;
    const int k0 = blockIdx.y * 64;
    const int t = threadIdx.x;
    {
        const int r = t >> 4, c = (t & 15) * 4;
        #pragma unroll
        for (int p = 0; p < 4; p++) {
            float4 v = *(const float4*)&W[(size_t)(k0 + r + p * 16) * NT + n0 + c];
            *(float4*)&tile[r + p * 16][c] = v;
        }
    }
    __syncthreads();
    const int nr = t >> 2;
    const int kc = (t & 3) * 16;
    u32t hi[8];
    #pragma unroll
    for (int j = 0; j < 8; j++)
        hi[j] = pk2(tile[kc + 2 * j][nr], tile[kc + 2 * j + 1][nr]);
    size_t ob = (size_t)(n0 + nr) * DIN + k0 + kc;
    *(uint4*)&Th[ob]     = *(uint4*)&hi[0];
    *(uint4*)&Th[ob + 8] = *(uint4*)&hi[4];
}

// ---------------- K0b: proj_out [k][y] fp32 -> WTh [y][k] bf16 RNE ----------------
__global__ __launch_bounds__(256) void transpose_w2(const float* __restrict__ W,
                                                    u16t* __restrict__ Th) {
    __shared__ float tile[64][68];
    const int n0 = blockIdx.x * 64;
    const int k0 = blockIdx.y * 64;
    const int t = threadIdx.x;
    {
        const int r = t >> 4, c = (t & 15) * 4;
        #pragma unroll
        for (int p = 0; p < 4; p++) {
            float4 v = *(const float4*)&W[(size_t)(k0 + r + p * 16) * 128 + n0 + c];
            *(float4*)&tile[r + p * 16][c] = v;
        }
    }
    __syncthreads();
    const int nr = t >> 2;
    const int kc = (t & 3) * 16;
    u32t hi[8];
    #pragma unroll
    for (int j = 0; j < 8; j++)
        hi[j] = pk2(tile[kc + 2 * j][nr], tile[kc + 2 * j + 1][nr]);
    size_t ob = (size_t)(n0 + nr) * KOUT + k0 + kc;
    *(uint4*)&Th[ob]     = *(uint4*)&hi[0];
    *(uint4*)&Th[ob + 8] = *(uint4*)&hi[4];
}

// ---------------- K1: qkv GEMM — pipelined dbuf, 1 barrier/iter, head-major epilogue ----------------
__global__ __launch_bounds__(256) void gemm_qkv4(const u16t* __restrict__ Ah,
                                                 const u16t* __restrict__ Bh,
                                                 const float* __restrict__ vb,
                                                 u16t* __restrict__ QB,
                                                 u16t* __restrict__ KB,
                                                 u16t* __restrict__ VF) {
    __shared__ __align__(16) u16t as_h[2][4 * 128 * 8];
    __shared__ __align__(16) u16t bs_h[2][4 * 128 * 8];

    const int t = threadIdx.x;
    const int lane = t & 63, wid = t >> 6;
    const int quad = lane >> 4, l15 = lane & 15;
    const int wm = (wid & 1) * 64;
    const int wn = (wid >> 1) * 64;
    const int tile = blockIdx.x;               // 0..47 = h*3 + {q,k,v}
    const int h = tile / 3, t3 = tile - h * 3;
    const int colBase = tile * 128;
    const int rowBase = blockIdx.y * 128;
    const int sm = t & 127;
    const int skh = t >> 7;

    f32x4 acc[4][4];
    #pragma unroll
    for (int i = 0; i < 4; i++)
        #pragma unroll
        for (int j = 0; j < 4; j++) acc[i][j] = (f32x4){0.f, 0.f, 0.f, 0.f};

    const u16t* aPtr = Ah + (size_t)(rowBase + sm) * DIN + skh * 16;
    const u16t* bPtr = Bh + (size_t)(colBase + sm) * DIN + skh * 16;
    const int swoff = (skh * 2) * 1024 + sm * 8;

    // prefetch tile 0
    uint4 a0 = *(const uint4*)(aPtr);
    uint4 a1 = *(const uint4*)(aPtr + 8);
    uint4 b0 = *(const uint4*)(bPtr);
    uint4 b1 = *(const uint4*)(bPtr + 8);

    for (int it = 0; it < 32; it++) {
        const int buf = it & 1;
        // commit (vmcnt waits here; loads had full prior compute phase)
        *(uint4*)(&as_h[buf][swoff])        = a0;
        *(uint4*)(&as_h[buf][swoff + 1024]) = a1;
        *(uint4*)(&bs_h[buf][swoff])        = b0;
        *(uint4*)(&bs_h[buf][swoff + 1024]) = b1;
        __syncthreads();          // no VM in flight -> cheap drain
        // issue next tile's loads (overlap compute below)
        {
            const int k0 = (it < 31) ? (it + 1) * 32 : it * 32;
            a0 = *(const uint4*)(aPtr + k0);
            a1 = *(const uint4*)(aPtr + k0 + 8);
            b0 = *(const uint4*)(bPtr + k0);
            b1 = *(const uint4*)(bPtr + k0 + 8);
        }
        bf16x8 ah[4], bh[4];
        #pragma unroll
        for (int mt = 0; mt < 4; mt++)
            ah[mt] = *(const bf16x8*)&as_h[buf][quad * 1024 + (wm + mt * 16 + l15) * 8];
        #pragma unroll
        for (int nt = 0; nt < 4; nt++)
            bh[nt] = *(const bf16x8*)&bs_h[buf][quad * 1024 + (wn + nt * 16 + l15) * 8];
        #pragma unroll
        for (int mt = 0; mt < 4; mt++)
            #pragma unroll
            for (int nt = 0; nt < 4; nt++)
                acc[mt][nt] = __builtin_amdgcn_mfma_f32_16x16x32_bf16(ah[mt], bh[nt], acc[mt][nt], 0, 0, 0);
    }

    const int z = rowBase >> 11;
    const int s0 = (rowBase & 2047) + wm + quad * 4;
    const size_t obase = (size_t)(z * 16 + h) * 2048;
    if (t3 == 2) {
        #pragma unroll
        for (int nt = 0; nt < 4; nt++) {
            int c = wn + nt * 16 + l15;
            float bb = vb[h * 128 + c];
            #pragma unroll
            for (int mt = 0; mt < 4; mt++)
                #pragma unroll
                for (int r = 0; r < 4; r++)
                    VF[(obase + s0 + mt * 16 + r) * 128 + c] = f2bf(acc[mt][nt][r] + bb);
        }
    } else {
        u16t* dst = t3 ? KB : QB;
        #pragma unroll
        for (int nt = 0; nt < 4; nt++) {
            int c = wn + nt * 16 + l15;
            #pragma unroll
            for (int mt = 0; mt < 4; mt++)
                #pragma unroll
                for (int r = 0; r < 4; r++)
                    dst[(obase + s0 + mt * 16 + r) * 128 + c] = f2bf(acc[mt][nt][r]);
        }
    }
}

// ---------------- K2: rotary in-place on QB/KB; V tile-transpose in-place ----------------
__global__ __launch_bounds__(256) void prep_rot_trans(u16t* __restrict__ QB,
                                                      u16t* __restrict__ KB,
                                                      u16t* __restrict__ VTh) {
    const int bx = blockIdx.x;
    const int st = bx & 63, h = (bx >> 6) & 15, z = bx >> 10;
    const int t = threadIdx.x;
    const size_t base = ((size_t)(z * 16 + h) * 2048 + st * 32) * 128;

    {
        const int r = t >> 3, w = t & 7;
        const int c = w & 3;
        const int s = st * 32 + r;
        u16t* buf = (w < 4) ? QB : KB;
        u16t* p1 = buf + base + (size_t)r * 128 + c * 16;
        u16t* p2 = p1 + 64;
        uint4 a0 = *(uint4*)p1, a1 = *(uint4*)(p1 + 8);
        uint4 b0 = *(uint4*)p2, b1 = *(uint4*)(p2 + 8);
        u32t A[8] = {a0.x, a0.y, a0.z, a0.w, a1.x, a1.y, a1.z, a1.w};
        u32t B[8] = {b0.x, b0.y, b0.z, b0.w, b1.x, b1.y, b1.z, b1.w};
        u32t OA[8], OB[8];
        #pragma unroll
        for (int p = 0; p < 8; p++) {
            float x1a = bf2f((u16t)(A[p] & 0xFFFFu)), x1b = bf2f((u16t)(A[p] >> 16));
            float x2a = bf2f((u16t)(B[p] & 0xFFFFu)), x2b = bf2f((u16t)(B[p] >> 16));
            int j0 = c * 16 + 2 * p;
            float f0 = expf(-0.14391156831212788f * (float)j0);
            float f1 = expf(-0.14391156831212788f * (float)(j0 + 1));
            float sn0, cs0, sn1, cs1;
            sincosf((float)s * f0, &sn0, &cs0);
            sincosf((float)s * f1, &sn1, &cs1);
            OA[p] = pk2(x1a * cs0 - x2a * sn0, x1b * cs1 - x2b * sn1);
            OB[p] = pk2(x2a * cs0 + x1a * sn0, x2b * cs1 + x1b * sn1);
        }
        *(uint4*)p1       = make_uint4(OA[0], OA[1], OA[2], OA[3]);
        *(uint4*)(p1 + 8) = make_uint4(OA[4], OA[5], OA[6], OA[7]);
        *(uint4*)p2       = make_uint4(OB[0], OB[1], OB[2], OB[3]);
        *(uint4*)(p2 + 8) = make_uint4(OB[4], OB[5], OB[6], OB[7]);
    }

    __shared__ u16t vt[128 * 40];
    {
        uint4 a = *(uint4*)(VTh + base + t * 16);
        uint4 b = *(uint4*)(VTh + base + t * 16 + 8);
        int row = t >> 3, d0 = (t & 7) * 16;
        u32t W[8] = {a.x, a.y, a.z, a.w, b.x, b.y, b.z, b.w};
        #pragma unroll
        for (int p = 0; p < 8; p++) {
            vt[(d0 + 2 * p) * 40 + row]     = (u16t)(W[p] & 0xFFFFu);
            vt[(d0 + 2 * p + 1) * 40 + row] = (u16t)(W[p] >> 16);
        }
    }
    __syncthreads();
    {
        int d = t >> 1, k0 = (t & 1) * 16;
        uint4 a = *(uint4*)&vt[d * 40 + k0];
        uint4 b = *(uint4*)&vt[d * 40 + k0 + 8];
        *(uint4*)(VTh + base + t * 16)     = a;
        *(uint4*)(VTh + base + t * 16 + 8) = b;
    }
}

// ---------------- K3: attention v7 — 128q, dbuf, loads AFTER barrier, 1 barrier/iter ----------------
#define ATTSCALE 0.08838834764831845f

__global__ __launch_bounds__(256, 2) void attn_kernel7(const u16t* __restrict__ QB,
                                                       const u16t* __restrict__ KB,
                                                       const u16t* __restrict__ VTh,
                                                       const int* __restrict__ mask,
                                                       u16t* __restrict__ O3b) {
    const int blk = blockIdx.x;
    const int qt = blk & 15;           // 16 q-blocks of 128
    const int h  = (blk >> 4) & 15;
    const int z  = blk >> 8;
    const int t  = threadIdx.x;
    const int lane = t & 63, wid = t >> 6;
    const int quad = lane >> 4, l15 = lane & 15;

    __shared__ __align__(16) u16t ks[2][32 * 136];   // K bf16 [key][d], double-buffered
    __shared__ __align__(16) u16t vth[2][128 * 40];  // V^T bf16 [d][key], double-buffered
    __shared__ __align__(16) u16t wlb[128 * 40];     // P bf16 [q][key] (wave-private rows)
    __shared__ int qm[128], km[2][32];

    const int q0 = qt * 128;
    const size_t zh = (size_t)(z * 16 + h);
    const u16t* qb  = QB  + zh * 262144;
    const u16t* kb  = KB  + zh * 262144;
    const u16t* vhg = VTh + zh * 262144;

    // wave owns q-16-tiles {2*wid, 2*wid+1}
    bf16x8 qf[2][4];
    #pragma unroll
    for (int i = 0; i < 2; i++)
        #pragma unroll
        for (int kk = 0; kk < 4; kk++)
            qf[i][kk] = *(const bf16x8*)(qb + (size_t)(q0 + 16 * (2 * wid + i) + l15) * 128 + kk * 32 + quad * 8);
    if (t < 128) qm[t] = mask[z * SQ + q0 + t];

    // staging maps
    const int srow = t >> 3, sco = (t & 7) * 16;     // K: [key srow][d sco..]
    const int sdd = t >> 1, sk0 = (t & 1) * 16;      // V: [d sdd][key sk0..]

    // prefetch tile 0
    uint4 ka, kb2, va, vb2;
    int kmv = 0;
    {
        ka  = *(const uint4*)(kb + t * 16);
        kb2 = *(const uint4*)(kb + t * 16 + 8);
        va  = *(const uint4*)(vhg + t * 16);
        vb2 = *(const uint4*)(vhg + t * 16 + 8);
        if (t < 32) kmv = mask[z * SQ + t];
    }

    f32x4 acc[2][8];
    #pragma unroll
    for (int i = 0; i < 2; i++)
        #pragma unroll
        for (int d = 0; d < 8; d++) acc[i][d] = (f32x4){0.f, 0.f, 0.f, 0.f};
    float dsum[2][4] = {{0.f, 0.f, 0.f, 0.f}, {0.f, 0.f, 0.f, 0.f}};

    for (int it = 0; it < 64; it++) {
        const int buf = it & 1;
        // commit prefetched tile (vmcnt wait lands here — loads had a full compute phase)
        *(uint4*)&ks[buf][srow * 136 + sco]     = ka;
        *(uint4*)&ks[buf][srow * 136 + sco + 8] = kb2;
        *(uint4*)&vth[buf][sdd * 40 + sk0]      = va;
        *(uint4*)&vth[buf][sdd * 40 + sk0 + 8]  = vb2;
        if (t < 32) km[buf][t] = kmv;

        __syncthreads();   // no VM in flight -> cheap drain; publishes buf

        // issue next tile's loads AFTER the barrier — they overlap this iter's compute
        {
            const int ktn = (it < 63) ? (it + 1) * 32 : it * 32;
            const u16t* src = kb + (size_t)ktn * 128 + t * 16;
            ka  = *(const uint4*)(src);
            kb2 = *(const uint4*)(src + 8);
            const u16t* srch = vhg + (size_t)(ktn >> 5) * 4096 + t * 16;
            va  = *(const uint4*)(srch);
            vb2 = *(const uint4*)(srch + 8);
            if (t < 32) kmv = mask[z * SQ + ktn + t];
        }

        // QK^T: 2 q-tiles x 2 key-cols, kf shared across q
        f32x4 s4[2][2];
        #pragma unroll
        for (int i = 0; i < 2; i++)
            #pragma unroll
            for (int n = 0; n < 2; n++) s4[i][n] = (f32x4){0.f, 0.f, 0.f, 0.f};
        #pragma unroll
        for (int kk = 0; kk < 4; kk++) {
            bf16x8 kf0 = *(const bf16x8*)&ks[buf][l15 * 136 + kk * 32 + quad * 8];
            bf16x8 kf1 = *(const bf16x8*)&ks[buf][(16 + l15) * 136 + kk * 32 + quad * 8];
            s4[0][0] = __builtin_amdgcn_mfma_f32_16x16x32_bf16(qf[0][kk], kf0, s4[0][0], 0, 0, 0);
            s4[0][1] = __builtin_amdgcn_mfma_f32_16x16x32_bf16(qf[0][kk], kf1, s4[0][1], 0, 0, 0);
            s4[1][0] = __builtin_amdgcn_mfma_f32_16x16x32_bf16(qf[1][kk], kf0, s4[1][0], 0, 0, 0);
            s4[1][1] = __builtin_amdgcn_mfma_f32_16x16x32_bf16(qf[1][kk], kf1, s4[1][1], 0, 0, 0);
        }
        {   // mask + exp -> bf16 P into wave-private LDS rows; fp32 denominator
            int colm0 = km[buf][l15], colm1 = km[buf][16 + l15];
            #pragma unroll
            for (int i = 0; i < 2; i++)
                #pragma unroll
                for (int r = 0; r < 4; r++) {
                    int row = 16 * (2 * wid + i) + 4 * quad + r;
                    int qmr = qm[row];
                    float w0 = (qmr | colm0) ? 0.f : __expf(s4[i][0][r] * ATTSCALE);
                    float w1 = (qmr | colm1) ? 0.f : __expf(s4[i][1][r] * ATTSCALE);
                    dsum[i][r] += w0 + w1;
                    wlb[row * 40 + l15]      = f2bf(w0);
                    wlb[row * 40 + 16 + l15] = f2bf(w1);
                }
        }
        // P·V: same-wave read-back (wave-private rows; lgkm ordering, no barrier)
        bf16x8 pa[2];
        #pragma unroll
        for (int i = 0; i < 2; i++)
            pa[i] = *(const bf16x8*)&wlb[(16 * (2 * wid + i) + l15) * 40 + quad * 8];
        #pragma unroll
        for (int dt = 0; dt < 8; dt++) {
            bf16x8 vh = *(const bf16x8*)&vth[buf][(16 * dt + l15) * 40 + quad * 8];
            acc[0][dt] = __builtin_amdgcn_mfma_f32_16x16x32_bf16(pa[0], vh, acc[0][dt], 0, 0, 0);
            acc[1][dt] = __builtin_amdgcn_mfma_f32_16x16x32_bf16(pa[1], vh, acc[1][dt], 0, 0, 0);
        }
    }

    // denominator: complete within wave — 16-lane shuffle reduce
    #pragma unroll
    for (int i = 0; i < 2; i++)
        #pragma unroll
        for (int r = 0; r < 4; r++) {
            float v = dsum[i][r];
            v += __shfl_xor(v, 1);
            v += __shfl_xor(v, 2);
            v += __shfl_xor(v, 4);
            v += __shfl_xor(v, 8);
            dsum[i][r] = v;
        }

    // epilogue: normalize, cube, write bf16 O in [m=z*2048+s][k=h*128+d]
    #pragma unroll
    for (int i = 0; i < 2; i++)
        #pragma unroll
        for (int r = 0; r < 4; r++) {
            int row = 16 * (2 * wid + i) + 4 * quad + r;
            float inv = dsum[i][r] > 0.f ? 1.f / dsum[i][r] : 0.f;
            u16t* dst = O3b + (size_t)(z * SQ + q0 + row) * KOUT + h * 128;
            #pragma unroll
            for (int dt = 0; dt < 8; dt++)
                dst[16 * dt + l15] = f2bf(cubef(acc[i][dt][r] * inv));
        }
}

// ---------------- K4: partial[s] = O3b[:, chunk] @ W[chunk, :] — pipelined, KSPLIT=16 ----------------
__global__ __launch_bounds__(256) void final_gemm3(const u16t* __restrict__ Ab,
                                                   const u16t* __restrict__ Bh,
                                                   float* __restrict__ part) {
    __shared__ __align__(16) u16t as_h[2][4 * 128 * 8];
    __shared__ __align__(16) u16t bs_h[2][4 * 128 * 8];

    const int t = threadIdx.x;
    const int lane = t & 63, wid = t >> 6;
    const int quad = lane >> 4, l15 = lane & 15;
    const int wm = (wid & 1) * 64;
    const int wn = (wid >> 1) * 64;
    const int rowBase = blockIdx.x * 128;
    const int kBase   = blockIdx.y * (KOUT / KSPLIT);   // 128
    const int sm = t & 127;
    const int skh = t >> 7;

    f32x4 acc[4][4];
    #pragma unroll
    for (int i = 0; i < 4; i++)
        #pragma unroll
        for (int j = 0; j < 4; j++) acc[i][j] = (f32x4){0.f, 0.f, 0.f, 0.f};

    const u16t* aPtr = Ab + (size_t)(rowBase + sm) * KOUT + kBase + skh * 16;
    const u16t* bPtr = Bh + (size_t)sm * KOUT + kBase + skh * 16;
    const int swoff = (skh * 2) * 1024 + sm * 8;

    uint4 a0 = *(const uint4*)(aPtr);
    uint4 a1 = *(const uint4*)(aPtr + 8);
    uint4 b0 = *(const uint4*)(bPtr);
    uint4 b1 = *(const uint4*)(bPtr + 8);

    const int NIT = (KOUT / KSPLIT) / 32;   // 4
    for (int it = 0; it < NIT; it++) {
        const int buf = it & 1;
        *(uint4*)(&as_h[buf][swoff])        = a0;
        *(uint4*)(&as_h[buf][swoff + 1024]) = a1;
        *(uint4*)(&bs_h[buf][swoff])        = b0;
        *(uint4*)(&bs_h[buf][swoff + 1024]) = b1;
        __syncthreads();
        {
            const int k0 = (it < NIT - 1) ? (it + 1) * 32 : it * 32;
            a0 = *(const uint4*)(aPtr + k0);
            a1 = *(const uint4*)(aPtr + k0 + 8);
            b0 = *(const uint4*)(bPtr + k0);
            b1 = *(const uint4*)(bPtr + k0 + 8);
        }
        bf16x8 ah[4], bh[4];
        #pragma unroll
        for (int mt = 0; mt < 4; mt++)
            ah[mt] = *(const bf16x8*)&as_h[buf][quad * 1024 + (wm + mt * 16 + l15) * 8];
        #pragma unroll
        for (int nt = 0; nt < 4; nt++)
            bh[nt] = *(const bf16x8*)&bs_h[buf][quad * 1024 + (wn + nt * 16 + l15) * 8];
        #pragma unroll
        for (int mt = 0; mt < 4; mt++)
            #pragma unroll
            for (int nt = 0; nt < 4; nt++)
                acc[mt][nt] = __builtin_amdgcn_mfma_f32_16x16x32_bf16(ah[mt], bh[nt], acc[mt][nt], 0, 0, 0);
    }

    float* pbase = part + (size_t)blockIdx.y * ((size_t)MROWS * 128);
    #pragma unroll
    for (int mt = 0; mt < 4; mt++)
        #pragma unroll
        for (int nt = 0; nt < 4; nt++) {
            int col = wn + nt * 16 + l15;
            #pragma unroll
            for (int r = 0; r < 4; r++) {
                int row = rowBase + wm + mt * 16 + quad * 4 + r;
                pbase[(size_t)row * 128 + col] = acc[mt][nt][r];
            }
        }
}

// ---------------- K5: out = cube(sum partials + bias) ----------------
__global__ __launch_bounds__(256) void reduce_bias_cube(const float* __restrict__ part,
                                                        const float* __restrict__ bias,
                                                        float* __restrict__ out) {
    const int idx = (blockIdx.x * 256 + threadIdx.x) * 4;
    float4 s = {0.f, 0.f, 0.f, 0.f};
    #pragma unroll
    for (int p = 0; p < KSPLIT; p++) {
        float4 v = *(const float4*)&part[(size_t)p * ((size_t)MROWS * 128) + idx];
        s.x += v.x; s.y += v.y; s.z += v.z; s.w += v.w;
    }
    float4 b = *(const float4*)&bias[idx & 127];
    float4 r;
    r.x = cubef(s.x + b.x);
    r.y = cubef(s.y + b.y);
    r.z = cubef(s.z + b.z);
    r.w = cubef(s.w + b.w);
    *(float4*)&out[idx] = r;
}

extern "C" void kernel_launch(void* const* d_in, const int* in_sizes, int n_in,
                              void* d_out, int out_size, void* d_ws, size_t ws_size,
                              hipStream_t stream) {
    const float* x        = (const float*)d_in[0];
    const int*   mask     = (const int*)d_in[1];
    const float* proj_in  = (const float*)d_in[2];
    const float* v_bias   = (const float*)d_in[3];
    const float* proj_out = (const float*)d_in[4];
    const float* po_bias  = (const float*)d_in[5];
    float* out = (float*)d_out;

    // ws layout (~72 MB):
    u16t* QB  = (u16t*)d_ws;                      // [z,h,s,d] bf16 16 MB
    u16t* KB  = QB + (size_t)8388608;             // 16 MB
    u16t* VTh = KB + (size_t)8388608;             // 16 MB ([s][d] from gemm, [d][s]-tiled after prep)
    u16t* xb  = VTh + (size_t)8388608;            // [4096,1024] bf16 8 MB
    u16t* O3b = xb + (size_t)4194304;             // [4096,2048] bf16 16 MB
    // pTh aliases O3b (dead before attn writes O3b; gemm reads complete first — stream order)
    u16t* pTh = O3b;                              // [6144,1024] bf16 12.6 MB
    // WTh + partials alias QB..VTh region (48 MB, dead after attn)
    u16t* WTh = QB;                               // [128,2048] bf16 0.5 MB
    float* partials = (float*)(WTh + (size_t)128 * KOUT);  // [16,4096,128] f32 33.5 MB

    bf16_x<<<(MROWS * DIN) / (256 * 8), 256, 0, stream>>>(x, xb);
    transpose_w<<<dim3(NT / 64, DIN / 64), 256, 0, stream>>>(proj_in, pTh);
    gemm_qkv4<<<dim3(48, MROWS / 128), 256, 0, stream>>>(xb, pTh, v_bias, QB, KB, VTh);
    prep_rot_trans<<<BZ * HH * (SQ / 32), 256, 0, stream>>>(QB, KB, VTh);
    attn_kernel7<<<BZ * HH * (SQ / 128), 256, 0, stream>>>(QB, KB, VTh, mask, O3b);
    transpose_w2<<<dim3(2, KOUT / 64), 256, 0, stream>>>(proj_out, WTh);
    final_gemm3<<<dim3(MROWS / 128, KSPLIT), 256, 0, stream>>>(O3b, WTh, partials);
    reduce_bias_cube<<<(MROWS * 128) / (256 * 4), 256, 0, stream>>>(partials, po_bias, out);
}